// Round 23
// baseline (2054.863 us; speedup 1.0000x reference)
//
#include <hip/hip_runtime.h>
#include <math.h>

#define EMBD   64
#define USERS  100000
#define ITEMS  50000
#define NODES  150000
#define NNZ_C  4500000
#define NENT   100000
#define EPER   16
#define NBLK_SCAN 586   // ceil(150000/256)

#define NBKT   512      // row buckets
#define BROWS  293      // rows per bucket (512*293 = 150016)
#define NCHK   2048     // edge chunks (1 wave each)
#define CHSZ   2198     // ceil(NNZ/NCHK): 2048*2198 = 4,501,504
#define HN     (NBKT * NCHK)      // 1,048,576
#define HBLK   (HN / 256)         // 4096
#define DMAX   1024     // degree bins for row sort

// ===========================================================================
// Eigen pexp_float replica (XLA:CPU vector exp) — EXACT copy of passing R9.
// ===========================================================================
__device__ __forceinline__ float eigen_expf(float x) {
    x = fminf(fmaxf(x, -87.33654785156250f), 88.72283935546875f);
    float m = floorf(__fmaf_rn(x, 1.44269504088896341f, 0.5f));
    float r = __fsub_rn(x, __fmul_rn(m, 0.693359375f));
    r = __fsub_rn(r, __fmul_rn(m, -2.12194440e-4f));
    float z = __fmul_rn(r, r);
    float y = 1.9875691500e-4f;
    y = __fmaf_rn(y, r, 1.3981999507e-3f);
    y = __fmaf_rn(y, r, 8.3334519073e-3f);
    y = __fmaf_rn(y, r, 4.1665795894e-2f);
    y = __fmaf_rn(y, r, 1.6666665459e-1f);
    y = __fmaf_rn(y, r, 5.0000001201e-1f);
    y = __fmaf_rn(y, z, r);
    y = __fadd_rn(y, 1.0f);
    int mi = (int)m;
    return __int_as_float(__float_as_int(y) + (mi << 23));
}

// ===========================================================================
// Eigen ptanh_float replica — EXACT copy of passing R9.
// ===========================================================================
__device__ __forceinline__ float eigen_tanhf(float x) {
    float ax = fabsf(x);
    float x2 = __fmul_rn(x, x);
    float p = -2.76076847742355e-16f;
    p = __fmaf_rn(p, x2, 2.00018790482477e-13f);
    p = __fmaf_rn(p, x2, -8.60467152213735e-11f);
    p = __fmaf_rn(p, x2, 5.12229709037114e-08f);
    p = __fmaf_rn(p, x2, 1.48572235717979e-05f);
    p = __fmaf_rn(p, x2, 6.37261928875436e-04f);
    p = __fmaf_rn(p, x2, 4.89352455891786e-03f);
    p = __fmul_rn(x, p);
    float q = 1.19825839466702e-06f;
    q = __fmaf_rn(q, x2, 1.18534705686654e-04f);
    q = __fmaf_rn(q, x2, 2.26843463243900e-03f);
    q = __fmaf_rn(q, x2, 4.89352518554385e-03f);
    float r = __fdiv_rn(p, q);
    return (ax < 4.0e-4f) ? x : r;
}

// wave_sum64 — bitwise identical to R9's np_sum64 (commutative-add pairings)
__device__ __forceinline__ float wave_sum64(float x) {
    float v = __fadd_rn(x, __shfl_xor(x, 16));
    v = __fadd_rn(v, __shfl_xor(v, 32));
    v = __fadd_rn(v, __shfl_xor(v, 8));
    v = __fadd_rn(v, __shfl_xor(v, 4));
    v = __fadd_rn(v, __shfl_xor(v, 2));
    v = __fadd_rn(v, __shfl_xor(v, 1));
    return v;
}

// exact wave-uniform broadcast via VALU readlane (no DS pipe)
__device__ __forceinline__ float rdlane(float v, int l) {
    return __int_as_float(__builtin_amdgcn_readlane(__float_as_int(v), l));
}

// lanes-with-equal-key mask via ballot rounds (deterministic, no atomics)
__device__ __forceinline__ unsigned long long match_mask10(int key) {
    unsigned long long m = ~0ull;
    #pragma unroll
    for (int bit = 0; bit < 10; ++bit) {
        unsigned long long bb = __ballot((key >> bit) & 1);
        m &= ((key >> bit) & 1) ? bb : ~bb;
    }
    return m;
}

// ===========================================================================
// rowptr scan kernels
// ===========================================================================
__global__ void scan1_kernel(const int* __restrict__ cnt, int* __restrict__ bsum) {
    __shared__ int s[256];
    int i = blockIdx.x * 256 + threadIdx.x;
    int v = (i < NODES) ? cnt[i] : 0;
    s[threadIdx.x] = v; __syncthreads();
    for (int o = 128; o; o >>= 1) {
        if (threadIdx.x < o) s[threadIdx.x] += s[threadIdx.x + o];
        __syncthreads();
    }
    if (threadIdx.x == 0) bsum[blockIdx.x] = s[0];
}

__global__ void scan2_kernel(int* __restrict__ bsum, int nblk) {
    if (blockIdx.x == 0 && threadIdx.x == 0) {
        int acc = 0;
        for (int b = 0; b < nblk; ++b) { int t = bsum[b]; bsum[b] = acc; acc += t; }
    }
}

__global__ void scan3_kernel(const int* __restrict__ cnt, const int* __restrict__ bsum,
                             int* __restrict__ rowptr) {
    __shared__ int s[256];
    int tid = threadIdx.x;
    int i = blockIdx.x * 256 + tid;
    int v = (i < NODES) ? cnt[i] : 0;
    s[tid] = v; __syncthreads();
    for (int o = 1; o < 256; o <<= 1) {
        int t = (tid >= o) ? s[tid - o] : 0;
        __syncthreads();
        s[tid] += t;
        __syncthreads();
    }
    if (i < NODES) rowptr[i] = bsum[blockIdx.x] + s[tid] - v;   // exclusive
}

// ===========================================================================
// Fused hist + row-count (R21/R22)
// ===========================================================================
__global__ __launch_bounds__(64) void hist_kernel(const int* __restrict__ rows,
                                                  int* __restrict__ H,
                                                  int* __restrict__ cnt) {
    __shared__ int h[NBKT];
    int lane = threadIdx.x;
    int w = blockIdx.x;
    for (int b = lane; b < NBKT; b += 64) h[b] = 0;
    __syncthreads();
    int start = w * CHSZ;
    int end = min(start + CHSZ, NNZ_C);
    for (int i = start + lane; i < end; i += 64) {
        int r = rows[i];
        atomicAdd(&h[r / BROWS], 1);
        atomicAdd(&cnt[r], 1);
    }
    __syncthreads();
    for (int b = lane; b < NBKT; b += 64) H[b * NCHK + w] = h[b];
}

// generic block-sum / final-scan kernels (grid = N/256)
__global__ void gscanA_kernel(const int* __restrict__ in, int* __restrict__ part) {
    __shared__ int s[256];
    int i = blockIdx.x * 256 + threadIdx.x;
    s[threadIdx.x] = in[i]; __syncthreads();
    for (int o = 128; o; o >>= 1) {
        if (threadIdx.x < o) s[threadIdx.x] += s[threadIdx.x + o];
        __syncthreads();
    }
    if (threadIdx.x == 0) part[blockIdx.x] = s[0];
}

__global__ void gscanC_kernel(const int* __restrict__ in, const int* __restrict__ part,
                              int* __restrict__ outp) {
    __shared__ int s[256];
    int tid = threadIdx.x;
    int i = blockIdx.x * 256 + tid;
    int v = in[i];
    s[tid] = v; __syncthreads();
    for (int o = 1; o < 256; o <<= 1) {
        int t = (tid >= o) ? s[tid - o] : 0;
        __syncthreads();
        s[tid] += t;
        __syncthreads();
    }
    outp[i] = part[blockIdx.x] + s[tid] - v;   // exclusive prefix
}

// ===========================================================================
// Stable scatter of edge ids into bucket-major store (R22)
// ===========================================================================
__global__ __launch_bounds__(64) void scatter1_kernel(const int* __restrict__ rows,
                                                      const int* __restrict__ P,
                                                      int* __restrict__ bids) {
    __shared__ int curL[NBKT];
    __shared__ int tmpB[NBKT];
    int lane = threadIdx.x;
    int w = blockIdx.x;
    for (int b = lane; b < NBKT; b += 64) curL[b] = P[b * NCHK + w];
    __syncthreads();
    int start = w * CHSZ;
    int end = min(start + CHSZ, NNZ_C);
    for (int i = start; i < end; i += 64) {
        int e = i + lane;
        bool ok = (e < end);
        int b = ok ? (rows[e] / BROWS) : 0;
        int key = ok ? b : (NBKT + lane);
        unsigned long long m = match_mask10(key);
        int rank = __popcll(m & ((1ull << lane) - 1ull));
        int cntk = __popcll(m);
        if (ok && rank == 0) {
            int base = curL[b];
            curL[b] = base + cntk;
            tmpB[b] = base;
        }
        __syncthreads();
        if (ok) bids[tmpB[b] + rank] = e;
        __syncthreads();
    }
}

__global__ __launch_bounds__(64) void place_kernel(const int* __restrict__ rows,
                                                   const int* __restrict__ cols,
                                                   const float* __restrict__ vals,
                                                   const int* __restrict__ bids,
                                                   const int* __restrict__ P,
                                                   const int* __restrict__ rowp,
                                                   int2* __restrict__ pairs) {
    __shared__ int curR[BROWS];
    __shared__ int tmpB[BROWS];
    int lane = threadIdx.x;
    int b0 = blockIdx.x;
    for (int j = lane; j < BROWS; j += 64) curR[j] = 0;
    __syncthreads();
    int bs = P[b0 * NCHK];
    int be = (b0 == NBKT - 1) ? NNZ_C : P[(b0 + 1) * NCHK];
    for (int i = bs; i < be; i += 64) {
        int idx = i + lane;
        bool ok = (idx < be);
        int e = ok ? bids[idx] : 0;
        int r = ok ? rows[e] : 0;
        int rl = r - b0 * BROWS;
        int key = ok ? rl : (NBKT + lane);
        unsigned long long m = match_mask10(key);
        int rank = __popcll(m & ((1ull << lane) - 1ull));
        int cntk = __popcll(m);
        if (ok && rank == 0) {
            int base = curR[rl];
            curR[rl] = base + cntk;
            tmpB[rl] = base;
        }
        __syncthreads();
        if (ok) {
            int slot = rowp[r] + tmpB[rl] + rank;
            pairs[slot] = make_int2(cols[e], __float_as_int(vals[e]));
        }
        __syncthreads();
    }
}

// ===========================================================================
// Degree-sorted row order (counting sort, descending degree).
// Order within a degree is atomic-nondeterministic — harmless: the wave->row
// map is a pure schedule permutation; each row's computation is independent.
// ===========================================================================
__global__ void dhist_kernel(const int* __restrict__ cnt, int* __restrict__ dh) {
    int r = blockIdx.x * 256 + threadIdx.x;
    if (r < NODES) atomicAdd(&dh[min(cnt[r], DMAX - 1)], 1);
}

__global__ void dscan_kernel(int* __restrict__ dh) {     // descending bases
    if (blockIdx.x == 0 && threadIdx.x == 0) {
        int acc = 0;
        for (int d = DMAX - 1; d >= 0; --d) { int t = dh[d]; dh[d] = acc; acc += t; }
    }
}

__global__ void dscatter_kernel(const int* __restrict__ cnt, int* __restrict__ dh,
                                int* __restrict__ rord) {
    int r = blockIdx.x * 256 + threadIdx.x;
    if (r < NODES) {
        int d = min(cnt[r], DMAX - 1);
        int slot = atomicAdd(&dh[d], 1);
        rord[slot] = r;
    }
}

// ===========================================================================
// Fused SpMM + layer epilogue — R16 arithmetic; wave w handles row rord[w]
// (degree-sorted schedule; per-row work unchanged => bitwise identical).
// ===========================================================================
#define NB 8
__global__ __launch_bounds__(256) void spmm_layer_kernel(
        const int*   __restrict__ rowptr,
        const int*   __restrict__ cnt,
        const int*   __restrict__ rord,
        const int2*  __restrict__ pairs,
        const float* __restrict__ x,
        float*       __restrict__ y,
        const float* __restrict__ noise_k,
        const float* __restrict__ nitems,
        float*       __restrict__ out,
        int k) {
    int lane = threadIdx.x & 63;
    int r0 = (blockIdx.x * blockDim.x + threadIdx.x) >> 6;
    if (r0 >= NODES) return;
    int r = __builtin_amdgcn_readfirstlane(rord[r0]);  // degree-sorted row
    int s = rowptr[r], n = cnt[r];
    const int2* p2 = pairs + s;

    float acc = 0.f;
    int i = 0;
    if (n >= NB) {
        float v[NB], g[NB];
        #pragma unroll
        for (int j = 0; j < NB; ++j) {
            int2 t = p2[j];
            v[j] = __int_as_float(t.y);
            g[j] = x[(size_t)t.x * EMBD + lane];
        }
        for (i = NB; i + NB <= n; i += NB) {
            float v2[NB], g2[NB];
            #pragma unroll
            for (int j = 0; j < NB; ++j) {
                int2 t = p2[i + j];
                v2[j] = __int_as_float(t.y);
                g2[j] = x[(size_t)t.x * EMBD + lane];
            }
            #pragma unroll
            for (int j = 0; j < NB; ++j)
                acc = __fadd_rn(acc, __fmul_rn(v[j], g[j]));
            #pragma unroll
            for (int j = 0; j < NB; ++j) { v[j] = v2[j]; g[j] = g2[j]; }
        }
        #pragma unroll
        for (int j = 0; j < NB; ++j)
            acc = __fadd_rn(acc, __fmul_rn(v[j], g[j]));
    }
    for (; i < n; ++i) {
        int2 t = p2[i];
        acc = __fadd_rn(acc, __fmul_rn(__int_as_float(t.y),
                                       x[(size_t)t.x * EMBD + lane]));
    }

    size_t idx = (size_t)r * EMBD + lane;
    float yv = acc;
    bool isu = (r < USERS);
    float v = isu ? noise_k[idx] : 0.f;
    float ss = wave_sum64(__fmul_rn(v, v));

    float nn;
    if (isu) nn = __fdiv_rn(v, fmaxf(__fsqrt_rn(ss), 1e-12f));
    else     nn = nitems[(size_t)(r - USERS) * EMBD + lane];

    float sg  = (yv > 0.f) ? 1.f : ((yv < 0.f) ? -1.f : 0.f);
    float ego = __fadd_rn(yv, __fmul_rn(__fmul_rn(sg, nn), 0.1f));

    y[idx] = ego;

    const size_t CL_OFF = (size_t)NODES * EMBD;
    if (k == 0) {
        out[idx]          = ego;
        out[CL_OFF + idx] = ego;
    } else if (k == 1) {
        out[idx] = __fadd_rn(out[idx], ego);
    } else {
        out[idx] = __fdiv_rn(__fadd_rn(out[idx], ego), 3.0f);
    }
}

// ===========================================================================
// GAT — EXACT R21/R22 version (hybrid readlane(0..5) + scalar(6..15); pass).
// ===========================================================================
__global__ __launch_bounds__(512) void gat_kernel(
        const float* __restrict__ item_emb,
        const float* __restrict__ ent_table,
        const float* __restrict__ fc_w,
        const float* __restrict__ fc_b,
        const float* __restrict__ rel_table,
        const int*   __restrict__ item_ents,
        const int*   __restrict__ item_rels,
        float*       __restrict__ nitems) {
    __shared__ float Wsh[128 * 64];        // fc_w, 32 KiB
    int tid = threadIdx.x;
    for (int i = tid; i < 128 * 64; i += 512) Wsh[i] = fc_w[i];
    __syncthreads();

    int w = tid >> 6, lane = tid & 63;
    int n = __builtin_amdgcn_readfirstlane(blockIdx.x * 8 + w);  // uniform item
    const float* qrow = item_emb + (size_t)n * EMBD;             // uniform base
    float q  = qrow[lane];
    float bv = fc_b[lane];

    float accI = 0.f;
    #pragma unroll 1
    for (int kb = 0; kb < 16; ++kb) {
        float4 qv = *(const float4*)(qrow + kb * 4);
        accI = __fmaf_rn(qv.x, Wsh[(kb * 4 + 0) * 64 + lane], accI);
        accI = __fmaf_rn(qv.y, Wsh[(kb * 4 + 1) * 64 + lane], accI);
        accI = __fmaf_rn(qv.z, Wsh[(kb * 4 + 2) * 64 + lane], accI);
        accI = __fmaf_rn(qv.w, Wsh[(kb * 4 + 3) * 64 + lane], accI);
    }

    int eid[EPER];
    const float* er[EPER];
    float ev[EPER];
    #pragma unroll
    for (int e = 0; e < EPER; ++e) {
        eid[e] = __builtin_amdgcn_readfirstlane(item_ents[n * EPER + e]);
        er[e]  = ent_table + (size_t)eid[e] * EMBD;
        ev[e]  = er[e][lane];
    }

    float acc[EPER];
    #pragma unroll
    for (int e = 0; e < EPER; ++e) acc[e] = accI;
    #pragma unroll 1
    for (int kb = 0; kb < 16; ++kb) {
        float4 sv[10];
        #pragma unroll
        for (int eo = 0; eo < 10; ++eo)
            sv[eo] = *(const float4*)(er[6 + eo] + kb * 4);
        float wv0 = Wsh[(64 + kb * 4 + 0) * 64 + lane];
        float wv1 = Wsh[(64 + kb * 4 + 1) * 64 + lane];
        float wv2 = Wsh[(64 + kb * 4 + 2) * 64 + lane];
        float wv3 = Wsh[(64 + kb * 4 + 3) * 64 + lane];
        int k0 = kb * 4;
        #pragma unroll
        for (int eo = 0; eo < 6; ++eo) {
            acc[eo] = __fmaf_rn(rdlane(ev[eo], k0 + 0), wv0, acc[eo]);
            acc[eo] = __fmaf_rn(rdlane(ev[eo], k0 + 1), wv1, acc[eo]);
            acc[eo] = __fmaf_rn(rdlane(ev[eo], k0 + 2), wv2, acc[eo]);
            acc[eo] = __fmaf_rn(rdlane(ev[eo], k0 + 3), wv3, acc[eo]);
        }
        #pragma unroll
        for (int eo = 0; eo < 10; ++eo)
            acc[6 + eo] = __fmaf_rn(sv[eo].x, wv0, acc[6 + eo]);
        #pragma unroll
        for (int eo = 0; eo < 10; ++eo)
            acc[6 + eo] = __fmaf_rn(sv[eo].y, wv1, acc[6 + eo]);
        #pragma unroll
        for (int eo = 0; eo < 10; ++eo)
            acc[6 + eo] = __fmaf_rn(sv[eo].z, wv2, acc[6 + eo]);
        #pragma unroll
        for (int eo = 0; eo < 10; ++eo)
            acc[6 + eo] = __fmaf_rn(sv[eo].w, wv3, acc[6 + eo]);
    }

    float s16[EPER];
    #pragma unroll
    for (int e = 0; e < EPER; ++e) {
        int rid = item_rels[n * EPER + e];
        float pe   = __fadd_rn(acc[e], bv);
        float prod = __fmul_rn(pe, rel_table[rid * EMBD + lane]);
        float esum = wave_sum64(prod);
        float sc = (esum >= 0.f) ? esum : __fmul_rn(0.2f, esum);   // leaky_relu
        s16[e] = (eid[e] != NENT) ? sc : -9.0e15f;                 // mask
    }

    float m = s16[0];
    #pragma unroll
    for (int e = 1; e < EPER; ++e) m = fmaxf(m, s16[e]);
    float a16[EPER];
    #pragma unroll
    for (int e = 0; e < EPER; ++e) a16[e] = eigen_expf(__fsub_rn(s16[e], m));
    float s8[8];
    #pragma unroll
    for (int j = 0; j < 8; ++j) s8[j] = __fadd_rn(a16[j], a16[j + 8]);
    float t40 = __fadd_rn(s8[0], s8[4]);
    float t41 = __fadd_rn(s8[1], s8[5]);
    float t42 = __fadd_rn(s8[2], s8[6]);
    float t43 = __fadd_rn(s8[3], s8[7]);
    float z = __fadd_rn(__fadd_rn(t40, t42), __fadd_rn(t41, t43));

    float agg = 0.f;
    #pragma unroll
    for (int e = 0; e < EPER; ++e)
        agg = __fmaf_rn(__fdiv_rn(a16[e], z), ev[e], agg);

    float o = __fadd_rn(agg, q);
    float t = eigen_tanhf(__fmul_rn(0.5f, o));     // XLA logistic
    float sig = __fmaf_rn(0.5f, t, 0.5f);

    float ss = wave_sum64(__fmul_rn(sig, sig));
    float nrm = fmaxf(__fsqrt_rn(ss), 1e-12f);
    nitems[(size_t)n * EMBD + lane] = __fdiv_rn(sig, nrm);
}

// ===========================================================================
extern "C" void kernel_launch(void* const* d_in, const int* in_sizes, int n_in,
                              void* d_out, int out_size, void* d_ws, size_t ws_size,
                              hipStream_t stream) {
    const float* user_emb   = (const float*)d_in[0];
    const float* item_emb   = (const float*)d_in[1];
    const float* ent_table  = (const float*)d_in[2];
    const float* rel_table  = (const float*)d_in[3];
    const float* fc_w       = (const float*)d_in[4];
    const float* fc_b       = (const float*)d_in[5];
    const int*   adj_rows   = (const int*)d_in[6];
    const int*   adj_cols   = (const int*)d_in[7];
    const float* adj_vals   = (const float*)d_in[8];
    const float* users_noise= (const float*)d_in[9];
    const int*   item_ents  = (const int*)d_in[10];
    const int*   item_rels  = (const int*)d_in[11];

    const size_t NE = (size_t)NODES * EMBD;        // 9.6M floats
    char* base = (char*)d_ws;
    size_t off = 0;
    float*  B0    = (float*)(base + off); off += NE * 4;
    float*  B1    = (float*)(base + off); off += NE * 4;
    float*  NIT   = (float*)(base + off); off += (size_t)ITEMS * EMBD * 4;
    int*    cnt   = (int*)(base + off);   off += 150016 * 4;
    int*    rowp  = (int*)(base + off);   off += 150016 * 4;
    int*    rord  = (int*)(base + off);   off += 150016 * 4;
    int*    bsum  = (int*)(base + off);   off += 1024 * 4;
    int*    dh    = (int*)(base + off);   off += DMAX * 4;
    int*    H     = (int*)(base + off);   off += (size_t)HN * 4;
    int*    gb    = (int*)(base + off);   off += (size_t)HBLK * 4;
    int*    g2    = (int*)(base + off);   off += 64 * 4;
    int*    gbE   = (int*)(base + off);   off += (size_t)HBLK * 4;
    int*    P     = (int*)(base + off);   off += (size_t)HN * 4;
    int*    bids  = (int*)(base + off);   off += (size_t)NNZ_C * 4;
    off = (off + 7) & ~(size_t)7;
    int2*   pairs = (int2*)(base + off);  off += (size_t)NNZ_C * 8;
    float*  out   = (float*)d_out;

    // ---- fused hist + row-count (one pass over rows; 2048 waves) ----
    hipMemsetAsync(cnt, 0, 150016 * 4, stream);
    hipMemsetAsync(dh, 0, DMAX * 4, stream);
    hist_kernel<<<NCHK, 64, 0, stream>>>(adj_rows, H, cnt);

    // ---- rowptr scan ----
    scan1_kernel<<<NBLK_SCAN, 256, 0, stream>>>(cnt, bsum);
    scan2_kernel<<<1, 64, 0, stream>>>(bsum, NBLK_SCAN);
    scan3_kernel<<<NBLK_SCAN, 256, 0, stream>>>(cnt, bsum, rowp);

    // ---- degree-sorted row order (descending) ----
    dhist_kernel<<<NBLK_SCAN, 256, 0, stream>>>(cnt, dh);
    dscan_kernel<<<1, 64, 0, stream>>>(dh);
    dscatter_kernel<<<NBLK_SCAN, 256, 0, stream>>>(cnt, dh, rord);

    // ---- bucket prefix (3-level over 1M) ----
    gscanA_kernel<<<HBLK, 256, 0, stream>>>(H, gb);
    gscanA_kernel<<<HBLK / 256, 256, 0, stream>>>(gb, g2);
    scan2_kernel<<<1, 64, 0, stream>>>(g2, HBLK / 256);
    gscanC_kernel<<<HBLK / 256, 256, 0, stream>>>(gb, g2, gbE);
    gscanC_kernel<<<HBLK, 256, 0, stream>>>(H, gbE, P);

    // ---- stable scatter (2048 waves) + placement ----
    scatter1_kernel<<<NCHK, 64, 0, stream>>>(adj_rows, P, bids);
    place_kernel<<<NBKT, 64, 0, stream>>>(adj_rows, adj_cols, adj_vals,
                                          bids, P, rowp, pairs);

    // ---- ego_0 = concat(user_emb, item_emb) ----
    hipMemcpyAsync(B0, user_emb, (size_t)USERS * EMBD * 4, hipMemcpyDeviceToDevice, stream);
    hipMemcpyAsync(B0 + (size_t)USERS * EMBD, item_emb, (size_t)ITEMS * EMBD * 4,
                   hipMemcpyDeviceToDevice, stream);

    gat_kernel<<<ITEMS / 8, 512, 0, stream>>>(item_emb, ent_table, fc_w, fc_b,
                                              rel_table, item_ents, item_rels, NIT);

    for (int k = 0; k < 3; ++k) {
        float* X = (k & 1) ? B1 : B0;
        float* Y = (k & 1) ? B0 : B1;
        spmm_layer_kernel<<<(NODES + 3) / 4, 256, 0, stream>>>(
            rowp, cnt, rord, pairs, X, Y,
            users_noise + (size_t)k * USERS * EMBD, NIT, out, k);
    }
}

// Round 24
// 1438.881 us; speedup vs baseline: 1.4281x; 1.4281x over previous
//
#include <hip/hip_runtime.h>
#include <math.h>

#define EMBD   64
#define USERS  100000
#define ITEMS  50000
#define NODES  150000
#define NNZ_C  4500000
#define NENT   100000
#define EPER   16
#define NBLK_SCAN 586   // ceil(150000/256)

#define NBKT   512      // row buckets
#define BROWS  293      // rows per bucket (512*293 = 150016)
#define NCHK   2048     // edge chunks (1 wave each)
#define CHSZ   2198     // ceil(NNZ/NCHK): 2048*2198 = 4,501,504
#define HN     (NBKT * NCHK)      // 1,048,576
#define HBLK   (HN / 256)         // 4096
#define DMAX   1024     // degree bins for row sort

// ===========================================================================
// Eigen pexp_float replica (XLA:CPU vector exp) — EXACT copy of passing R9.
// ===========================================================================
__device__ __forceinline__ float eigen_expf(float x) {
    x = fminf(fmaxf(x, -87.33654785156250f), 88.72283935546875f);
    float m = floorf(__fmaf_rn(x, 1.44269504088896341f, 0.5f));
    float r = __fsub_rn(x, __fmul_rn(m, 0.693359375f));
    r = __fsub_rn(r, __fmul_rn(m, -2.12194440e-4f));
    float z = __fmul_rn(r, r);
    float y = 1.9875691500e-4f;
    y = __fmaf_rn(y, r, 1.3981999507e-3f);
    y = __fmaf_rn(y, r, 8.3334519073e-3f);
    y = __fmaf_rn(y, r, 4.1665795894e-2f);
    y = __fmaf_rn(y, r, 1.6666665459e-1f);
    y = __fmaf_rn(y, r, 5.0000001201e-1f);
    y = __fmaf_rn(y, z, r);
    y = __fadd_rn(y, 1.0f);
    int mi = (int)m;
    return __int_as_float(__float_as_int(y) + (mi << 23));
}

// ===========================================================================
// Eigen ptanh_float replica — EXACT copy of passing R9.
// ===========================================================================
__device__ __forceinline__ float eigen_tanhf(float x) {
    float ax = fabsf(x);
    float x2 = __fmul_rn(x, x);
    float p = -2.76076847742355e-16f;
    p = __fmaf_rn(p, x2, 2.00018790482477e-13f);
    p = __fmaf_rn(p, x2, -8.60467152213735e-11f);
    p = __fmaf_rn(p, x2, 5.12229709037114e-08f);
    p = __fmaf_rn(p, x2, 1.48572235717979e-05f);
    p = __fmaf_rn(p, x2, 6.37261928875436e-04f);
    p = __fmaf_rn(p, x2, 4.89352455891786e-03f);
    p = __fmul_rn(x, p);
    float q = 1.19825839466702e-06f;
    q = __fmaf_rn(q, x2, 1.18534705686654e-04f);
    q = __fmaf_rn(q, x2, 2.26843463243900e-03f);
    q = __fmaf_rn(q, x2, 4.89352518554385e-03f);
    float r = __fdiv_rn(p, q);
    return (ax < 4.0e-4f) ? x : r;
}

// wave_sum64 — bitwise identical to R9's np_sum64 (commutative-add pairings)
__device__ __forceinline__ float wave_sum64(float x) {
    float v = __fadd_rn(x, __shfl_xor(x, 16));
    v = __fadd_rn(v, __shfl_xor(v, 32));
    v = __fadd_rn(v, __shfl_xor(v, 8));
    v = __fadd_rn(v, __shfl_xor(v, 4));
    v = __fadd_rn(v, __shfl_xor(v, 2));
    v = __fadd_rn(v, __shfl_xor(v, 1));
    return v;
}

// exact wave-uniform broadcast via VALU readlane (no DS pipe)
__device__ __forceinline__ float rdlane(float v, int l) {
    return __int_as_float(__builtin_amdgcn_readlane(__float_as_int(v), l));
}

// lanes-with-equal-key mask via ballot rounds (deterministic, no atomics)
__device__ __forceinline__ unsigned long long match_mask10(int key) {
    unsigned long long m = ~0ull;
    #pragma unroll
    for (int bit = 0; bit < 10; ++bit) {
        unsigned long long bb = __ballot((key >> bit) & 1);
        m &= ((key >> bit) & 1) ? bb : ~bb;
    }
    return m;
}

// ===========================================================================
// rowptr scan kernels
// ===========================================================================
__global__ void scan1_kernel(const int* __restrict__ cnt, int* __restrict__ bsum) {
    __shared__ int s[256];
    int i = blockIdx.x * 256 + threadIdx.x;
    int v = (i < NODES) ? cnt[i] : 0;
    s[threadIdx.x] = v; __syncthreads();
    for (int o = 128; o; o >>= 1) {
        if (threadIdx.x < o) s[threadIdx.x] += s[threadIdx.x + o];
        __syncthreads();
    }
    if (threadIdx.x == 0) bsum[blockIdx.x] = s[0];
}

__global__ void scan2_kernel(int* __restrict__ bsum, int nblk) {
    if (blockIdx.x == 0 && threadIdx.x == 0) {
        int acc = 0;
        for (int b = 0; b < nblk; ++b) { int t = bsum[b]; bsum[b] = acc; acc += t; }
    }
}

__global__ void scan3_kernel(const int* __restrict__ cnt, const int* __restrict__ bsum,
                             int* __restrict__ rowptr) {
    __shared__ int s[256];
    int tid = threadIdx.x;
    int i = blockIdx.x * 256 + tid;
    int v = (i < NODES) ? cnt[i] : 0;
    s[tid] = v; __syncthreads();
    for (int o = 1; o < 256; o <<= 1) {
        int t = (tid >= o) ? s[tid - o] : 0;
        __syncthreads();
        s[tid] += t;
        __syncthreads();
    }
    if (i < NODES) rowptr[i] = bsum[blockIdx.x] + s[tid] - v;   // exclusive
}

// ===========================================================================
// Fused hist + row-count (R21/R22)
// ===========================================================================
__global__ __launch_bounds__(64) void hist_kernel(const int* __restrict__ rows,
                                                  int* __restrict__ H,
                                                  int* __restrict__ cnt) {
    __shared__ int h[NBKT];
    int lane = threadIdx.x;
    int w = blockIdx.x;
    for (int b = lane; b < NBKT; b += 64) h[b] = 0;
    __syncthreads();
    int start = w * CHSZ;
    int end = min(start + CHSZ, NNZ_C);
    for (int i = start + lane; i < end; i += 64) {
        int r = rows[i];
        atomicAdd(&h[r / BROWS], 1);
        atomicAdd(&cnt[r], 1);
    }
    __syncthreads();
    for (int b = lane; b < NBKT; b += 64) H[b * NCHK + w] = h[b];
}

// generic block-sum / final-scan kernels (grid = N/256)
__global__ void gscanA_kernel(const int* __restrict__ in, int* __restrict__ part) {
    __shared__ int s[256];
    int i = blockIdx.x * 256 + threadIdx.x;
    s[threadIdx.x] = in[i]; __syncthreads();
    for (int o = 128; o; o >>= 1) {
        if (threadIdx.x < o) s[threadIdx.x] += s[threadIdx.x + o];
        __syncthreads();
    }
    if (threadIdx.x == 0) part[blockIdx.x] = s[0];
}

__global__ void gscanC_kernel(const int* __restrict__ in, const int* __restrict__ part,
                              int* __restrict__ outp) {
    __shared__ int s[256];
    int tid = threadIdx.x;
    int i = blockIdx.x * 256 + tid;
    int v = in[i];
    s[tid] = v; __syncthreads();
    for (int o = 1; o < 256; o <<= 1) {
        int t = (tid >= o) ? s[tid - o] : 0;
        __syncthreads();
        s[tid] += t;
        __syncthreads();
    }
    outp[i] = part[blockIdx.x] + s[tid] - v;   // exclusive prefix
}

// ===========================================================================
// Stable scatter of edge ids into bucket-major store (R22)
// ===========================================================================
__global__ __launch_bounds__(64) void scatter1_kernel(const int* __restrict__ rows,
                                                      const int* __restrict__ P,
                                                      int* __restrict__ bids) {
    __shared__ int curL[NBKT];
    __shared__ int tmpB[NBKT];
    int lane = threadIdx.x;
    int w = blockIdx.x;
    for (int b = lane; b < NBKT; b += 64) curL[b] = P[b * NCHK + w];
    __syncthreads();
    int start = w * CHSZ;
    int end = min(start + CHSZ, NNZ_C);
    for (int i = start; i < end; i += 64) {
        int e = i + lane;
        bool ok = (e < end);
        int b = ok ? (rows[e] / BROWS) : 0;
        int key = ok ? b : (NBKT + lane);
        unsigned long long m = match_mask10(key);
        int rank = __popcll(m & ((1ull << lane) - 1ull));
        int cntk = __popcll(m);
        if (ok && rank == 0) {
            int base = curL[b];
            curL[b] = base + cntk;
            tmpB[b] = base;
        }
        __syncthreads();
        if (ok) bids[tmpB[b] + rank] = e;
        __syncthreads();
    }
}

__global__ __launch_bounds__(64) void place_kernel(const int* __restrict__ rows,
                                                   const int* __restrict__ cols,
                                                   const float* __restrict__ vals,
                                                   const int* __restrict__ bids,
                                                   const int* __restrict__ P,
                                                   const int* __restrict__ rowp,
                                                   int2* __restrict__ pairs) {
    __shared__ int curR[BROWS];
    __shared__ int tmpB[BROWS];
    int lane = threadIdx.x;
    int b0 = blockIdx.x;
    for (int j = lane; j < BROWS; j += 64) curR[j] = 0;
    __syncthreads();
    int bs = P[b0 * NCHK];
    int be = (b0 == NBKT - 1) ? NNZ_C : P[(b0 + 1) * NCHK];
    for (int i = bs; i < be; i += 64) {
        int idx = i + lane;
        bool ok = (idx < be);
        int e = ok ? bids[idx] : 0;
        int r = ok ? rows[e] : 0;
        int rl = r - b0 * BROWS;
        int key = ok ? rl : (NBKT + lane);
        unsigned long long m = match_mask10(key);
        int rank = __popcll(m & ((1ull << lane) - 1ull));
        int cntk = __popcll(m);
        if (ok && rank == 0) {
            int base = curR[rl];
            curR[rl] = base + cntk;
            tmpB[rl] = base;
        }
        __syncthreads();
        if (ok) {
            int slot = rowp[r] + tmpB[rl] + rank;
            pairs[slot] = make_int2(cols[e], __float_as_int(vals[e]));
        }
        __syncthreads();
    }
}

// ===========================================================================
// Degree-sorted row order — LDS-privatized counting sort (contention-free).
// dhist_v2: per-block LDS histogram, one global add per (block, bin).
// dscatter_v2: LDS local ranks + per-(block,bin) global reservation.
// Within-degree order nondeterministic — harmless (pure schedule permutation).
// ===========================================================================
__global__ __launch_bounds__(256) void dhist_kernel(const int* __restrict__ cnt,
                                                    int* __restrict__ dh) {
    __shared__ int lh[DMAX];
    int tid = threadIdx.x;
    for (int d = tid; d < DMAX; d += 256) lh[d] = 0;
    __syncthreads();
    int r = blockIdx.x * 256 + tid;
    if (r < NODES) atomicAdd(&lh[min(cnt[r], DMAX - 1)], 1);
    __syncthreads();
    for (int d = tid; d < DMAX; d += 256)
        if (lh[d]) atomicAdd(&dh[d], lh[d]);
}

__global__ void dscan_kernel(int* __restrict__ dh) {     // descending bases
    if (blockIdx.x == 0 && threadIdx.x == 0) {
        int acc = 0;
        for (int d = DMAX - 1; d >= 0; --d) { int t = dh[d]; dh[d] = acc; acc += t; }
    }
}

__global__ __launch_bounds__(256) void dscatter_kernel(const int* __restrict__ cnt,
                                                       int* __restrict__ dh,
                                                       int* __restrict__ rord) {
    __shared__ int lh[DMAX];
    __shared__ int lbase[DMAX];
    int tid = threadIdx.x;
    for (int d = tid; d < DMAX; d += 256) lh[d] = 0;
    __syncthreads();
    int r = blockIdx.x * 256 + tid;
    int d = -1, lrank = 0;
    if (r < NODES) {
        d = min(cnt[r], DMAX - 1);
        lrank = atomicAdd(&lh[d], 1);
    }
    __syncthreads();
    for (int dd = tid; dd < DMAX; dd += 256)
        if (lh[dd]) lbase[dd] = atomicAdd(&dh[dd], lh[dd]);
    __syncthreads();
    if (r < NODES) rord[lbase[d] + lrank] = r;
}

// ===========================================================================
// Fused SpMM + layer epilogue — R16 arithmetic; wave w handles row rord[w].
// ===========================================================================
#define NB 8
__global__ __launch_bounds__(256) void spmm_layer_kernel(
        const int*   __restrict__ rowptr,
        const int*   __restrict__ cnt,
        const int*   __restrict__ rord,
        const int2*  __restrict__ pairs,
        const float* __restrict__ x,
        float*       __restrict__ y,
        const float* __restrict__ noise_k,
        const float* __restrict__ nitems,
        float*       __restrict__ out,
        int k) {
    int lane = threadIdx.x & 63;
    int r0 = (blockIdx.x * blockDim.x + threadIdx.x) >> 6;
    if (r0 >= NODES) return;
    int r = __builtin_amdgcn_readfirstlane(rord[r0]);  // degree-sorted row
    int s = rowptr[r], n = cnt[r];
    const int2* p2 = pairs + s;

    float acc = 0.f;
    int i = 0;
    if (n >= NB) {
        float v[NB], g[NB];
        #pragma unroll
        for (int j = 0; j < NB; ++j) {
            int2 t = p2[j];
            v[j] = __int_as_float(t.y);
            g[j] = x[(size_t)t.x * EMBD + lane];
        }
        for (i = NB; i + NB <= n; i += NB) {
            float v2[NB], g2[NB];
            #pragma unroll
            for (int j = 0; j < NB; ++j) {
                int2 t = p2[i + j];
                v2[j] = __int_as_float(t.y);
                g2[j] = x[(size_t)t.x * EMBD + lane];
            }
            #pragma unroll
            for (int j = 0; j < NB; ++j)
                acc = __fadd_rn(acc, __fmul_rn(v[j], g[j]));
            #pragma unroll
            for (int j = 0; j < NB; ++j) { v[j] = v2[j]; g[j] = g2[j]; }
        }
        #pragma unroll
        for (int j = 0; j < NB; ++j)
            acc = __fadd_rn(acc, __fmul_rn(v[j], g[j]));
    }
    for (; i < n; ++i) {
        int2 t = p2[i];
        acc = __fadd_rn(acc, __fmul_rn(__int_as_float(t.y),
                                       x[(size_t)t.x * EMBD + lane]));
    }

    size_t idx = (size_t)r * EMBD + lane;
    float yv = acc;
    bool isu = (r < USERS);
    float v = isu ? noise_k[idx] : 0.f;
    float ss = wave_sum64(__fmul_rn(v, v));

    float nn;
    if (isu) nn = __fdiv_rn(v, fmaxf(__fsqrt_rn(ss), 1e-12f));
    else     nn = nitems[(size_t)(r - USERS) * EMBD + lane];

    float sg  = (yv > 0.f) ? 1.f : ((yv < 0.f) ? -1.f : 0.f);
    float ego = __fadd_rn(yv, __fmul_rn(__fmul_rn(sg, nn), 0.1f));

    y[idx] = ego;

    const size_t CL_OFF = (size_t)NODES * EMBD;
    if (k == 0) {
        out[idx]          = ego;
        out[CL_OFF + idx] = ego;
    } else if (k == 1) {
        out[idx] = __fadd_rn(out[idx], ego);
    } else {
        out[idx] = __fdiv_rn(__fadd_rn(out[idx], ego), 3.0f);
    }
}

// ===========================================================================
// GAT — EXACT R21/R22 version (hybrid readlane(0..5) + scalar(6..15); pass).
// ===========================================================================
__global__ __launch_bounds__(512) void gat_kernel(
        const float* __restrict__ item_emb,
        const float* __restrict__ ent_table,
        const float* __restrict__ fc_w,
        const float* __restrict__ fc_b,
        const float* __restrict__ rel_table,
        const int*   __restrict__ item_ents,
        const int*   __restrict__ item_rels,
        float*       __restrict__ nitems) {
    __shared__ float Wsh[128 * 64];        // fc_w, 32 KiB
    int tid = threadIdx.x;
    for (int i = tid; i < 128 * 64; i += 512) Wsh[i] = fc_w[i];
    __syncthreads();

    int w = tid >> 6, lane = tid & 63;
    int n = __builtin_amdgcn_readfirstlane(blockIdx.x * 8 + w);  // uniform item
    const float* qrow = item_emb + (size_t)n * EMBD;             // uniform base
    float q  = qrow[lane];
    float bv = fc_b[lane];

    float accI = 0.f;
    #pragma unroll 1
    for (int kb = 0; kb < 16; ++kb) {
        float4 qv = *(const float4*)(qrow + kb * 4);
        accI = __fmaf_rn(qv.x, Wsh[(kb * 4 + 0) * 64 + lane], accI);
        accI = __fmaf_rn(qv.y, Wsh[(kb * 4 + 1) * 64 + lane], accI);
        accI = __fmaf_rn(qv.z, Wsh[(kb * 4 + 2) * 64 + lane], accI);
        accI = __fmaf_rn(qv.w, Wsh[(kb * 4 + 3) * 64 + lane], accI);
    }

    int eid[EPER];
    const float* er[EPER];
    float ev[EPER];
    #pragma unroll
    for (int e = 0; e < EPER; ++e) {
        eid[e] = __builtin_amdgcn_readfirstlane(item_ents[n * EPER + e]);
        er[e]  = ent_table + (size_t)eid[e] * EMBD;
        ev[e]  = er[e][lane];
    }

    float acc[EPER];
    #pragma unroll
    for (int e = 0; e < EPER; ++e) acc[e] = accI;
    #pragma unroll 1
    for (int kb = 0; kb < 16; ++kb) {
        float4 sv[10];
        #pragma unroll
        for (int eo = 0; eo < 10; ++eo)
            sv[eo] = *(const float4*)(er[6 + eo] + kb * 4);
        float wv0 = Wsh[(64 + kb * 4 + 0) * 64 + lane];
        float wv1 = Wsh[(64 + kb * 4 + 1) * 64 + lane];
        float wv2 = Wsh[(64 + kb * 4 + 2) * 64 + lane];
        float wv3 = Wsh[(64 + kb * 4 + 3) * 64 + lane];
        int k0 = kb * 4;
        #pragma unroll
        for (int eo = 0; eo < 6; ++eo) {
            acc[eo] = __fmaf_rn(rdlane(ev[eo], k0 + 0), wv0, acc[eo]);
            acc[eo] = __fmaf_rn(rdlane(ev[eo], k0 + 1), wv1, acc[eo]);
            acc[eo] = __fmaf_rn(rdlane(ev[eo], k0 + 2), wv2, acc[eo]);
            acc[eo] = __fmaf_rn(rdlane(ev[eo], k0 + 3), wv3, acc[eo]);
        }
        #pragma unroll
        for (int eo = 0; eo < 10; ++eo)
            acc[6 + eo] = __fmaf_rn(sv[eo].x, wv0, acc[6 + eo]);
        #pragma unroll
        for (int eo = 0; eo < 10; ++eo)
            acc[6 + eo] = __fmaf_rn(sv[eo].y, wv1, acc[6 + eo]);
        #pragma unroll
        for (int eo = 0; eo < 10; ++eo)
            acc[6 + eo] = __fmaf_rn(sv[eo].z, wv2, acc[6 + eo]);
        #pragma unroll
        for (int eo = 0; eo < 10; ++eo)
            acc[6 + eo] = __fmaf_rn(sv[eo].w, wv3, acc[6 + eo]);
    }

    float s16[EPER];
    #pragma unroll
    for (int e = 0; e < EPER; ++e) {
        int rid = item_rels[n * EPER + e];
        float pe   = __fadd_rn(acc[e], bv);
        float prod = __fmul_rn(pe, rel_table[rid * EMBD + lane]);
        float esum = wave_sum64(prod);
        float sc = (esum >= 0.f) ? esum : __fmul_rn(0.2f, esum);   // leaky_relu
        s16[e] = (eid[e] != NENT) ? sc : -9.0e15f;                 // mask
    }

    float m = s16[0];
    #pragma unroll
    for (int e = 1; e < EPER; ++e) m = fmaxf(m, s16[e]);
    float a16[EPER];
    #pragma unroll
    for (int e = 0; e < EPER; ++e) a16[e] = eigen_expf(__fsub_rn(s16[e], m));
    float s8[8];
    #pragma unroll
    for (int j = 0; j < 8; ++j) s8[j] = __fadd_rn(a16[j], a16[j + 8]);
    float t40 = __fadd_rn(s8[0], s8[4]);
    float t41 = __fadd_rn(s8[1], s8[5]);
    float t42 = __fadd_rn(s8[2], s8[6]);
    float t43 = __fadd_rn(s8[3], s8[7]);
    float z = __fadd_rn(__fadd_rn(t40, t42), __fadd_rn(t41, t43));

    float agg = 0.f;
    #pragma unroll
    for (int e = 0; e < EPER; ++e)
        agg = __fmaf_rn(__fdiv_rn(a16[e], z), ev[e], agg);

    float o = __fadd_rn(agg, q);
    float t = eigen_tanhf(__fmul_rn(0.5f, o));     // XLA logistic
    float sig = __fmaf_rn(0.5f, t, 0.5f);

    float ss = wave_sum64(__fmul_rn(sig, sig));
    float nrm = fmaxf(__fsqrt_rn(ss), 1e-12f);
    nitems[(size_t)n * EMBD + lane] = __fdiv_rn(sig, nrm);
}

// ===========================================================================
extern "C" void kernel_launch(void* const* d_in, const int* in_sizes, int n_in,
                              void* d_out, int out_size, void* d_ws, size_t ws_size,
                              hipStream_t stream) {
    const float* user_emb   = (const float*)d_in[0];
    const float* item_emb   = (const float*)d_in[1];
    const float* ent_table  = (const float*)d_in[2];
    const float* rel_table  = (const float*)d_in[3];
    const float* fc_w       = (const float*)d_in[4];
    const float* fc_b       = (const float*)d_in[5];
    const int*   adj_rows   = (const int*)d_in[6];
    const int*   adj_cols   = (const int*)d_in[7];
    const float* adj_vals   = (const float*)d_in[8];
    const float* users_noise= (const float*)d_in[9];
    const int*   item_ents  = (const int*)d_in[10];
    const int*   item_rels  = (const int*)d_in[11];

    const size_t NE = (size_t)NODES * EMBD;        // 9.6M floats
    char* base = (char*)d_ws;
    size_t off = 0;
    float*  B0    = (float*)(base + off); off += NE * 4;
    float*  B1    = (float*)(base + off); off += NE * 4;
    float*  NIT   = (float*)(base + off); off += (size_t)ITEMS * EMBD * 4;
    int*    cnt   = (int*)(base + off);   off += 150016 * 4;
    int*    rowp  = (int*)(base + off);   off += 150016 * 4;
    int*    rord  = (int*)(base + off);   off += 150016 * 4;
    int*    bsum  = (int*)(base + off);   off += 1024 * 4;
    int*    dh    = (int*)(base + off);   off += DMAX * 4;
    int*    H     = (int*)(base + off);   off += (size_t)HN * 4;
    int*    gb    = (int*)(base + off);   off += (size_t)HBLK * 4;
    int*    g2    = (int*)(base + off);   off += 64 * 4;
    int*    gbE   = (int*)(base + off);   off += (size_t)HBLK * 4;
    int*    P     = (int*)(base + off);   off += (size_t)HN * 4;
    int*    bids  = (int*)(base + off);   off += (size_t)NNZ_C * 4;
    off = (off + 7) & ~(size_t)7;
    int2*   pairs = (int2*)(base + off);  off += (size_t)NNZ_C * 8;
    float*  out   = (float*)d_out;

    // ---- fused hist + row-count (one pass over rows; 2048 waves) ----
    hipMemsetAsync(cnt, 0, 150016 * 4, stream);
    hipMemsetAsync(dh, 0, DMAX * 4, stream);
    hist_kernel<<<NCHK, 64, 0, stream>>>(adj_rows, H, cnt);

    // ---- rowptr scan ----
    scan1_kernel<<<NBLK_SCAN, 256, 0, stream>>>(cnt, bsum);
    scan2_kernel<<<1, 64, 0, stream>>>(bsum, NBLK_SCAN);
    scan3_kernel<<<NBLK_SCAN, 256, 0, stream>>>(cnt, bsum, rowp);

    // ---- degree-sorted row order (descending; LDS-privatized sort) ----
    dhist_kernel<<<NBLK_SCAN, 256, 0, stream>>>(cnt, dh);
    dscan_kernel<<<1, 64, 0, stream>>>(dh);
    dscatter_kernel<<<NBLK_SCAN, 256, 0, stream>>>(cnt, dh, rord);

    // ---- bucket prefix (3-level over 1M) ----
    gscanA_kernel<<<HBLK, 256, 0, stream>>>(H, gb);
    gscanA_kernel<<<HBLK / 256, 256, 0, stream>>>(gb, g2);
    scan2_kernel<<<1, 64, 0, stream>>>(g2, HBLK / 256);
    gscanC_kernel<<<HBLK / 256, 256, 0, stream>>>(gb, g2, gbE);
    gscanC_kernel<<<HBLK, 256, 0, stream>>>(H, gbE, P);

    // ---- stable scatter (2048 waves) + placement ----
    scatter1_kernel<<<NCHK, 64, 0, stream>>>(adj_rows, P, bids);
    place_kernel<<<NBKT, 64, 0, stream>>>(adj_rows, adj_cols, adj_vals,
                                          bids, P, rowp, pairs);

    // ---- ego_0 = concat(user_emb, item_emb) ----
    hipMemcpyAsync(B0, user_emb, (size_t)USERS * EMBD * 4, hipMemcpyDeviceToDevice, stream);
    hipMemcpyAsync(B0 + (size_t)USERS * EMBD, item_emb, (size_t)ITEMS * EMBD * 4,
                   hipMemcpyDeviceToDevice, stream);

    gat_kernel<<<ITEMS / 8, 512, 0, stream>>>(item_emb, ent_table, fc_w, fc_b,
                                              rel_table, item_ents, item_rels, NIT);

    for (int k = 0; k < 3; ++k) {
        float* X = (k & 1) ? B1 : B0;
        float* Y = (k & 1) ? B0 : B1;
        spmm_layer_kernel<<<(NODES + 3) / 4, 256, 0, stream>>>(
            rowp, cnt, rord, pairs, X, Y,
            users_noise + (size_t)k * USERS * EMBD, NIT, out, k);
    }
}

// Round 25
// 1342.892 us; speedup vs baseline: 1.5302x; 1.0715x over previous
//
#include <hip/hip_runtime.h>
#include <math.h>

#define EMBD   64
#define USERS  100000
#define ITEMS  50000
#define NODES  150000
#define NNZ_C  4500000
#define NENT   100000
#define EPER   16
#define NBLK_SCAN 586   // ceil(150000/256)

#define NBKT   512      // row buckets
#define BROWS  293      // rows per bucket (512*293 = 150016)
#define NCHK   2048     // edge chunks (1 wave each)
#define CHSZ   2198     // ceil(NNZ/NCHK): 2048*2198 = 4,501,504
#define HN     (NBKT * NCHK)      // 1,048,576
#define HBLK   (HN / 256)         // 4096

// ===========================================================================
// Eigen pexp_float replica (XLA:CPU vector exp) — EXACT copy of passing R9.
// ===========================================================================
__device__ __forceinline__ float eigen_expf(float x) {
    x = fminf(fmaxf(x, -87.33654785156250f), 88.72283935546875f);
    float m = floorf(__fmaf_rn(x, 1.44269504088896341f, 0.5f));
    float r = __fsub_rn(x, __fmul_rn(m, 0.693359375f));
    r = __fsub_rn(r, __fmul_rn(m, -2.12194440e-4f));
    float z = __fmul_rn(r, r);
    float y = 1.9875691500e-4f;
    y = __fmaf_rn(y, r, 1.3981999507e-3f);
    y = __fmaf_rn(y, r, 8.3334519073e-3f);
    y = __fmaf_rn(y, r, 4.1665795894e-2f);
    y = __fmaf_rn(y, r, 1.6666665459e-1f);
    y = __fmaf_rn(y, r, 5.0000001201e-1f);
    y = __fmaf_rn(y, z, r);
    y = __fadd_rn(y, 1.0f);
    int mi = (int)m;
    return __int_as_float(__float_as_int(y) + (mi << 23));
}

// ===========================================================================
// Eigen ptanh_float replica — EXACT copy of passing R9.
// ===========================================================================
__device__ __forceinline__ float eigen_tanhf(float x) {
    float ax = fabsf(x);
    float x2 = __fmul_rn(x, x);
    float p = -2.76076847742355e-16f;
    p = __fmaf_rn(p, x2, 2.00018790482477e-13f);
    p = __fmaf_rn(p, x2, -8.60467152213735e-11f);
    p = __fmaf_rn(p, x2, 5.12229709037114e-08f);
    p = __fmaf_rn(p, x2, 1.48572235717979e-05f);
    p = __fmaf_rn(p, x2, 6.37261928875436e-04f);
    p = __fmaf_rn(p, x2, 4.89352455891786e-03f);
    p = __fmul_rn(x, p);
    float q = 1.19825839466702e-06f;
    q = __fmaf_rn(q, x2, 1.18534705686654e-04f);
    q = __fmaf_rn(q, x2, 2.26843463243900e-03f);
    q = __fmaf_rn(q, x2, 4.89352518554385e-03f);
    float r = __fdiv_rn(p, q);
    return (ax < 4.0e-4f) ? x : r;
}

// wave_sum64 — bitwise identical to R9's np_sum64 (commutative-add pairings)
__device__ __forceinline__ float wave_sum64(float x) {
    float v = __fadd_rn(x, __shfl_xor(x, 16));
    v = __fadd_rn(v, __shfl_xor(v, 32));
    v = __fadd_rn(v, __shfl_xor(v, 8));
    v = __fadd_rn(v, __shfl_xor(v, 4));
    v = __fadd_rn(v, __shfl_xor(v, 2));
    v = __fadd_rn(v, __shfl_xor(v, 1));
    return v;
}

// exact wave-uniform broadcast via VALU readlane (no DS pipe)
__device__ __forceinline__ float rdlane(float v, int l) {
    return __int_as_float(__builtin_amdgcn_readlane(__float_as_int(v), l));
}

// lanes-with-equal-key mask via ballot rounds (deterministic, no atomics)
__device__ __forceinline__ unsigned long long match_mask10(int key) {
    unsigned long long m = ~0ull;
    #pragma unroll
    for (int bit = 0; bit < 10; ++bit) {
        unsigned long long bb = __ballot((key >> bit) & 1);
        m &= ((key >> bit) & 1) ? bb : ~bb;
    }
    return m;
}

// ===========================================================================
// rowptr scan kernels
// ===========================================================================
__global__ void scan1_kernel(const int* __restrict__ cnt, int* __restrict__ bsum) {
    __shared__ int s[256];
    int i = blockIdx.x * 256 + threadIdx.x;
    int v = (i < NODES) ? cnt[i] : 0;
    s[threadIdx.x] = v; __syncthreads();
    for (int o = 128; o; o >>= 1) {
        if (threadIdx.x < o) s[threadIdx.x] += s[threadIdx.x + o];
        __syncthreads();
    }
    if (threadIdx.x == 0) bsum[blockIdx.x] = s[0];
}

__global__ void scan2_kernel(int* __restrict__ bsum, int nblk) {
    if (blockIdx.x == 0 && threadIdx.x == 0) {
        int acc = 0;
        for (int b = 0; b < nblk; ++b) { int t = bsum[b]; bsum[b] = acc; acc += t; }
    }
}

__global__ void scan3_kernel(const int* __restrict__ cnt, const int* __restrict__ bsum,
                             int* __restrict__ rowptr) {
    __shared__ int s[256];
    int tid = threadIdx.x;
    int i = blockIdx.x * 256 + tid;
    int v = (i < NODES) ? cnt[i] : 0;
    s[tid] = v; __syncthreads();
    for (int o = 1; o < 256; o <<= 1) {
        int t = (tid >= o) ? s[tid - o] : 0;
        __syncthreads();
        s[tid] += t;
        __syncthreads();
    }
    if (i < NODES) rowptr[i] = bsum[blockIdx.x] + s[tid] - v;   // exclusive
}

// ===========================================================================
// Fused hist + row-count (R21/R22)
// ===========================================================================
__global__ __launch_bounds__(64) void hist_kernel(const int* __restrict__ rows,
                                                  int* __restrict__ H,
                                                  int* __restrict__ cnt) {
    __shared__ int h[NBKT];
    int lane = threadIdx.x;
    int w = blockIdx.x;
    for (int b = lane; b < NBKT; b += 64) h[b] = 0;
    __syncthreads();
    int start = w * CHSZ;
    int end = min(start + CHSZ, NNZ_C);
    for (int i = start + lane; i < end; i += 64) {
        int r = rows[i];
        atomicAdd(&h[r / BROWS], 1);
        atomicAdd(&cnt[r], 1);
    }
    __syncthreads();
    for (int b = lane; b < NBKT; b += 64) H[b * NCHK + w] = h[b];
}

// generic block-sum / final-scan kernels (grid = N/256)
__global__ void gscanA_kernel(const int* __restrict__ in, int* __restrict__ part) {
    __shared__ int s[256];
    int i = blockIdx.x * 256 + threadIdx.x;
    s[threadIdx.x] = in[i]; __syncthreads();
    for (int o = 128; o; o >>= 1) {
        if (threadIdx.x < o) s[threadIdx.x] += s[threadIdx.x + o];
        __syncthreads();
    }
    if (threadIdx.x == 0) part[blockIdx.x] = s[0];
}

__global__ void gscanC_kernel(const int* __restrict__ in, const int* __restrict__ part,
                              int* __restrict__ outp) {
    __shared__ int s[256];
    int tid = threadIdx.x;
    int i = blockIdx.x * 256 + tid;
    int v = in[i];
    s[tid] = v; __syncthreads();
    for (int o = 1; o < 256; o <<= 1) {
        int t = (tid >= o) ? s[tid - o] : 0;
        __syncthreads();
        s[tid] += t;
        __syncthreads();
    }
    outp[i] = part[blockIdx.x] + s[tid] - v;   // exclusive prefix
}

// ===========================================================================
// Stable scatter of edge ids into bucket-major store (R22)
// ===========================================================================
__global__ __launch_bounds__(64) void scatter1_kernel(const int* __restrict__ rows,
                                                      const int* __restrict__ P,
                                                      int* __restrict__ bids) {
    __shared__ int curL[NBKT];
    __shared__ int tmpB[NBKT];
    int lane = threadIdx.x;
    int w = blockIdx.x;
    for (int b = lane; b < NBKT; b += 64) curL[b] = P[b * NCHK + w];
    __syncthreads();
    int start = w * CHSZ;
    int end = min(start + CHSZ, NNZ_C);
    for (int i = start; i < end; i += 64) {
        int e = i + lane;
        bool ok = (e < end);
        int b = ok ? (rows[e] / BROWS) : 0;
        int key = ok ? b : (NBKT + lane);
        unsigned long long m = match_mask10(key);
        int rank = __popcll(m & ((1ull << lane) - 1ull));
        int cntk = __popcll(m);
        if (ok && rank == 0) {
            int base = curL[b];
            curL[b] = base + cntk;
            tmpB[b] = base;
        }
        __syncthreads();
        if (ok) bids[tmpB[b] + rank] = e;
        __syncthreads();
    }
}

__global__ __launch_bounds__(64) void place_kernel(const int* __restrict__ rows,
                                                   const int* __restrict__ cols,
                                                   const float* __restrict__ vals,
                                                   const int* __restrict__ bids,
                                                   const int* __restrict__ P,
                                                   const int* __restrict__ rowp,
                                                   int2* __restrict__ pairs) {
    __shared__ int curR[BROWS];
    __shared__ int tmpB[BROWS];
    int lane = threadIdx.x;
    int b0 = blockIdx.x;
    for (int j = lane; j < BROWS; j += 64) curR[j] = 0;
    __syncthreads();
    int bs = P[b0 * NCHK];
    int be = (b0 == NBKT - 1) ? NNZ_C : P[(b0 + 1) * NCHK];
    for (int i = bs; i < be; i += 64) {
        int idx = i + lane;
        bool ok = (idx < be);
        int e = ok ? bids[idx] : 0;
        int r = ok ? rows[e] : 0;
        int rl = r - b0 * BROWS;
        int key = ok ? rl : (NBKT + lane);
        unsigned long long m = match_mask10(key);
        int rank = __popcll(m & ((1ull << lane) - 1ull));
        int cntk = __popcll(m);
        if (ok && rank == 0) {
            int base = curR[rl];
            curR[rl] = base + cntk;
            tmpB[rl] = base;
        }
        __syncthreads();
        if (ok) {
            int slot = rowp[r] + tmpB[rl] + rank;
            pairs[slot] = make_int2(cols[e], __float_as_int(vals[e]));
        }
        __syncthreads();
    }
}

// ===========================================================================
// Fused SpMM + layer epilogue — EXACT R16/R20/R21/R22 version (known-pass).
// ===========================================================================
#define NB 8
__global__ __launch_bounds__(256) void spmm_layer_kernel(
        const int*   __restrict__ rowptr,
        const int*   __restrict__ cnt,
        const int2*  __restrict__ pairs,
        const float* __restrict__ x,
        float*       __restrict__ y,
        const float* __restrict__ noise_k,
        const float* __restrict__ nitems,
        float*       __restrict__ out,
        int k) {
    int lane = threadIdx.x & 63;
    int r0 = (blockIdx.x * blockDim.x + threadIdx.x) >> 6;
    if (r0 >= NODES) return;
    int r = __builtin_amdgcn_readfirstlane(r0);
    int s = rowptr[r], n = cnt[r];
    const int2* p2 = pairs + s;

    float acc = 0.f;
    int i = 0;
    if (n >= NB) {
        float v[NB], g[NB];
        #pragma unroll
        for (int j = 0; j < NB; ++j) {
            int2 t = p2[j];
            v[j] = __int_as_float(t.y);
            g[j] = x[(size_t)t.x * EMBD + lane];
        }
        for (i = NB; i + NB <= n; i += NB) {
            float v2[NB], g2[NB];
            #pragma unroll
            for (int j = 0; j < NB; ++j) {
                int2 t = p2[i + j];
                v2[j] = __int_as_float(t.y);
                g2[j] = x[(size_t)t.x * EMBD + lane];
            }
            #pragma unroll
            for (int j = 0; j < NB; ++j)
                acc = __fadd_rn(acc, __fmul_rn(v[j], g[j]));
            #pragma unroll
            for (int j = 0; j < NB; ++j) { v[j] = v2[j]; g[j] = g2[j]; }
        }
        #pragma unroll
        for (int j = 0; j < NB; ++j)
            acc = __fadd_rn(acc, __fmul_rn(v[j], g[j]));
    }
    for (; i < n; ++i) {
        int2 t = p2[i];
        acc = __fadd_rn(acc, __fmul_rn(__int_as_float(t.y),
                                       x[(size_t)t.x * EMBD + lane]));
    }

    size_t idx = (size_t)r * EMBD + lane;
    float yv = acc;
    bool isu = (r < USERS);
    float v = isu ? noise_k[idx] : 0.f;
    float ss = wave_sum64(__fmul_rn(v, v));

    float nn;
    if (isu) nn = __fdiv_rn(v, fmaxf(__fsqrt_rn(ss), 1e-12f));
    else     nn = nitems[(size_t)(r - USERS) * EMBD + lane];

    float sg  = (yv > 0.f) ? 1.f : ((yv < 0.f) ? -1.f : 0.f);
    float ego = __fadd_rn(yv, __fmul_rn(__fmul_rn(sg, nn), 0.1f));

    y[idx] = ego;

    const size_t CL_OFF = (size_t)NODES * EMBD;
    if (k == 0) {
        out[idx]          = ego;
        out[CL_OFF + idx] = ego;
    } else if (k == 1) {
        out[idx] = __fadd_rn(out[idx], ego);
    } else {
        out[idx] = __fdiv_rn(__fadd_rn(out[idx], ego), 3.0f);
    }
}

// ===========================================================================
// GAT — EXACT R21/R22 version (hybrid readlane(0..5) + scalar(6..15); pass).
// ===========================================================================
__global__ __launch_bounds__(512) void gat_kernel(
        const float* __restrict__ item_emb,
        const float* __restrict__ ent_table,
        const float* __restrict__ fc_w,
        const float* __restrict__ fc_b,
        const float* __restrict__ rel_table,
        const int*   __restrict__ item_ents,
        const int*   __restrict__ item_rels,
        float*       __restrict__ nitems) {
    __shared__ float Wsh[128 * 64];        // fc_w, 32 KiB
    int tid = threadIdx.x;
    for (int i = tid; i < 128 * 64; i += 512) Wsh[i] = fc_w[i];
    __syncthreads();

    int w = tid >> 6, lane = tid & 63;
    int n = __builtin_amdgcn_readfirstlane(blockIdx.x * 8 + w);  // uniform item
    const float* qrow = item_emb + (size_t)n * EMBD;             // uniform base
    float q  = qrow[lane];
    float bv = fc_b[lane];

    float accI = 0.f;
    #pragma unroll 1
    for (int kb = 0; kb < 16; ++kb) {
        float4 qv = *(const float4*)(qrow + kb * 4);
        accI = __fmaf_rn(qv.x, Wsh[(kb * 4 + 0) * 64 + lane], accI);
        accI = __fmaf_rn(qv.y, Wsh[(kb * 4 + 1) * 64 + lane], accI);
        accI = __fmaf_rn(qv.z, Wsh[(kb * 4 + 2) * 64 + lane], accI);
        accI = __fmaf_rn(qv.w, Wsh[(kb * 4 + 3) * 64 + lane], accI);
    }

    int eid[EPER];
    const float* er[EPER];
    float ev[EPER];
    #pragma unroll
    for (int e = 0; e < EPER; ++e) {
        eid[e] = __builtin_amdgcn_readfirstlane(item_ents[n * EPER + e]);
        er[e]  = ent_table + (size_t)eid[e] * EMBD;
        ev[e]  = er[e][lane];
    }

    float acc[EPER];
    #pragma unroll
    for (int e = 0; e < EPER; ++e) acc[e] = accI;
    #pragma unroll 1
    for (int kb = 0; kb < 16; ++kb) {
        float4 sv[10];
        #pragma unroll
        for (int eo = 0; eo < 10; ++eo)
            sv[eo] = *(const float4*)(er[6 + eo] + kb * 4);
        float wv0 = Wsh[(64 + kb * 4 + 0) * 64 + lane];
        float wv1 = Wsh[(64 + kb * 4 + 1) * 64 + lane];
        float wv2 = Wsh[(64 + kb * 4 + 2) * 64 + lane];
        float wv3 = Wsh[(64 + kb * 4 + 3) * 64 + lane];
        int k0 = kb * 4;
        #pragma unroll
        for (int eo = 0; eo < 6; ++eo) {
            acc[eo] = __fmaf_rn(rdlane(ev[eo], k0 + 0), wv0, acc[eo]);
            acc[eo] = __fmaf_rn(rdlane(ev[eo], k0 + 1), wv1, acc[eo]);
            acc[eo] = __fmaf_rn(rdlane(ev[eo], k0 + 2), wv2, acc[eo]);
            acc[eo] = __fmaf_rn(rdlane(ev[eo], k0 + 3), wv3, acc[eo]);
        }
        #pragma unroll
        for (int eo = 0; eo < 10; ++eo)
            acc[6 + eo] = __fmaf_rn(sv[eo].x, wv0, acc[6 + eo]);
        #pragma unroll
        for (int eo = 0; eo < 10; ++eo)
            acc[6 + eo] = __fmaf_rn(sv[eo].y, wv1, acc[6 + eo]);
        #pragma unroll
        for (int eo = 0; eo < 10; ++eo)
            acc[6 + eo] = __fmaf_rn(sv[eo].z, wv2, acc[6 + eo]);
        #pragma unroll
        for (int eo = 0; eo < 10; ++eo)
            acc[6 + eo] = __fmaf_rn(sv[eo].w, wv3, acc[6 + eo]);
    }

    float s16[EPER];
    #pragma unroll
    for (int e = 0; e < EPER; ++e) {
        int rid = item_rels[n * EPER + e];
        float pe   = __fadd_rn(acc[e], bv);
        float prod = __fmul_rn(pe, rel_table[rid * EMBD + lane]);
        float esum = wave_sum64(prod);
        float sc = (esum >= 0.f) ? esum : __fmul_rn(0.2f, esum);   // leaky_relu
        s16[e] = (eid[e] != NENT) ? sc : -9.0e15f;                 // mask
    }

    float m = s16[0];
    #pragma unroll
    for (int e = 1; e < EPER; ++e) m = fmaxf(m, s16[e]);
    float a16[EPER];
    #pragma unroll
    for (int e = 0; e < EPER; ++e) a16[e] = eigen_expf(__fsub_rn(s16[e], m));
    float s8[8];
    #pragma unroll
    for (int j = 0; j < 8; ++j) s8[j] = __fadd_rn(a16[j], a16[j + 8]);
    float t40 = __fadd_rn(s8[0], s8[4]);
    float t41 = __fadd_rn(s8[1], s8[5]);
    float t42 = __fadd_rn(s8[2], s8[6]);
    float t43 = __fadd_rn(s8[3], s8[7]);
    float z = __fadd_rn(__fadd_rn(t40, t42), __fadd_rn(t41, t43));

    float agg = 0.f;
    #pragma unroll
    for (int e = 0; e < EPER; ++e)
        agg = __fmaf_rn(__fdiv_rn(a16[e], z), ev[e], agg);

    float o = __fadd_rn(agg, q);
    float t = eigen_tanhf(__fmul_rn(0.5f, o));     // XLA logistic
    float sig = __fmaf_rn(0.5f, t, 0.5f);

    float ss = wave_sum64(__fmul_rn(sig, sig));
    float nrm = fmaxf(__fsqrt_rn(ss), 1e-12f);
    nitems[(size_t)n * EMBD + lane] = __fdiv_rn(sig, nrm);
}

// ===========================================================================
extern "C" void kernel_launch(void* const* d_in, const int* in_sizes, int n_in,
                              void* d_out, int out_size, void* d_ws, size_t ws_size,
                              hipStream_t stream) {
    const float* user_emb   = (const float*)d_in[0];
    const float* item_emb   = (const float*)d_in[1];
    const float* ent_table  = (const float*)d_in[2];
    const float* rel_table  = (const float*)d_in[3];
    const float* fc_w       = (const float*)d_in[4];
    const float* fc_b       = (const float*)d_in[5];
    const int*   adj_rows   = (const int*)d_in[6];
    const int*   adj_cols   = (const int*)d_in[7];
    const float* adj_vals   = (const float*)d_in[8];
    const float* users_noise= (const float*)d_in[9];
    const int*   item_ents  = (const int*)d_in[10];
    const int*   item_rels  = (const int*)d_in[11];

    const size_t NE = (size_t)NODES * EMBD;        // 9.6M floats
    char* base = (char*)d_ws;
    size_t off = 0;
    float*  B0    = (float*)(base + off); off += NE * 4;
    float*  B1    = (float*)(base + off); off += NE * 4;
    float*  NIT   = (float*)(base + off); off += (size_t)ITEMS * EMBD * 4;
    int*    cnt   = (int*)(base + off);   off += 150016 * 4;
    int*    rowp  = (int*)(base + off);   off += 150016 * 4;
    int*    bsum  = (int*)(base + off);   off += 1024 * 4;
    int*    H     = (int*)(base + off);   off += (size_t)HN * 4;
    int*    gb    = (int*)(base + off);   off += (size_t)HBLK * 4;   // 4096
    int*    g2    = (int*)(base + off);   off += 64 * 4;             // 16 used
    int*    gbE   = (int*)(base + off);   off += (size_t)HBLK * 4;
    int*    P     = (int*)(base + off);   off += (size_t)HN * 4;
    int*    bids  = (int*)(base + off);   off += (size_t)NNZ_C * 4;
    off = (off + 7) & ~(size_t)7;
    int2*   pairs = (int2*)(base + off);  off += (size_t)NNZ_C * 8;
    float*  out   = (float*)d_out;

    // ---- fused hist + row-count (one pass over rows; 2048 waves) ----
    hipMemsetAsync(cnt, 0, 150016 * 4, stream);
    hist_kernel<<<NCHK, 64, 0, stream>>>(adj_rows, H, cnt);

    // ---- rowptr scan ----
    scan1_kernel<<<NBLK_SCAN, 256, 0, stream>>>(cnt, bsum);
    scan2_kernel<<<1, 64, 0, stream>>>(bsum, NBLK_SCAN);
    scan3_kernel<<<NBLK_SCAN, 256, 0, stream>>>(cnt, bsum, rowp);

    // ---- bucket prefix (3-level over 1M) ----
    gscanA_kernel<<<HBLK, 256, 0, stream>>>(H, gb);        // 4096 block sums
    gscanA_kernel<<<HBLK / 256, 256, 0, stream>>>(gb, g2); // 16 sums
    scan2_kernel<<<1, 64, 0, stream>>>(g2, HBLK / 256);
    gscanC_kernel<<<HBLK / 256, 256, 0, stream>>>(gb, g2, gbE);  // excl prefix of gb
    gscanC_kernel<<<HBLK, 256, 0, stream>>>(H, gbE, P);          // excl prefix of H

    // ---- stable scatter (2048 waves) + placement ----
    scatter1_kernel<<<NCHK, 64, 0, stream>>>(adj_rows, P, bids);
    place_kernel<<<NBKT, 64, 0, stream>>>(adj_rows, adj_cols, adj_vals,
                                          bids, P, rowp, pairs);

    // ---- ego_0 = concat(user_emb, item_emb) ----
    hipMemcpyAsync(B0, user_emb, (size_t)USERS * EMBD * 4, hipMemcpyDeviceToDevice, stream);
    hipMemcpyAsync(B0 + (size_t)USERS * EMBD, item_emb, (size_t)ITEMS * EMBD * 4,
                   hipMemcpyDeviceToDevice, stream);

    gat_kernel<<<ITEMS / 8, 512, 0, stream>>>(item_emb, ent_table, fc_w, fc_b,
                                              rel_table, item_ents, item_rels, NIT);

    for (int k = 0; k < 3; ++k) {
        float* X = (k & 1) ? B1 : B0;
        float* Y = (k & 1) ? B0 : B1;
        spmm_layer_kernel<<<(NODES + 3) / 4, 256, 0, stream>>>(
            rowp, cnt, pairs, X, Y,
            users_noise + (size_t)k * USERS * EMBD, NIT, out, k);
    }
}